// Round 2
// baseline (871.939 us; speedup 1.0000x reference)
//
#include <hip/hip_runtime.h>

typedef __bf16 bf16x8 __attribute__((ext_vector_type(8)));
typedef float floatx4 __attribute__((ext_vector_type(4)));

__device__ __forceinline__ unsigned short f2bf_bits(float f) {
  __bf16 h = (__bf16)f;
  return __builtin_bit_cast(unsigned short, h);
}

// ---------------------------------------------------------------------------
// Pf[h][k][c] = pre_h[k] * K1_h[k][c]   (f32, c contiguous)
// h: 0->(pre1,K1=cos_kernel2) 1->(pre2,sin_kernel2) 2->(pre3,sin_kernel3)
//    3->(pre4,cos_kernel4)
// ---------------------------------------------------------------------------
__global__ __launch_bounds__(256) void k_prep_p(
    const float* __restrict__ pre1, const float* __restrict__ pre2,
    const float* __restrict__ pre3, const float* __restrict__ pre4,
    const float* __restrict__ ck2, const float* __restrict__ sk2,
    const float* __restrict__ sk3, const float* __restrict__ ck4,
    float* __restrict__ Pf)
{
  int idx = blockIdx.x * 256 + threadIdx.x;        // 4*9216 threads exact
  int h = idx / 9216;
  int rem = idx - h * 9216;
  int k = rem / 96;
  const float* pre = (h == 0) ? pre1 : (h == 1) ? pre2 : (h == 2) ? pre3 : pre4;
  const float* K1  = (h == 0) ? ck2  : (h == 1) ? sk2  : (h == 2) ? sk3  : ck4;
  Pf[idx] = pre[k] * K1[rem];
}

// ---------------------------------------------------------------------------
// Qrot[i][h][c][r] = post_h[rr] * K2_h[rr*96+c],  rr = (r-i) mod 96   (bf16)
// h: 0->(post1,K2=cos_kernel1) 1->(post2,sin_kernel1) 2->(post3,cos_kernel3)
//    3->(post4,sin_kernel4)
// All 96 rotations of Q precomputed so stage1's MFMA A-operand is a plain
// aligned contiguous load (rotation on the contraction axis would otherwise
// force misaligned bf16 vector reads).
// ---------------------------------------------------------------------------
__global__ __launch_bounds__(256) void k_prep_q(
    const float* __restrict__ post1, const float* __restrict__ post2,
    const float* __restrict__ post3, const float* __restrict__ post4,
    const float* __restrict__ ck1, const float* __restrict__ sk1,
    const float* __restrict__ ck3, const float* __restrict__ sk4,
    unsigned short* __restrict__ Qrot)
{
  int idx = blockIdx.x * 256 + threadIdx.x;        // 96*4*9216 threads exact
  int i = idx / 36864;
  int rem = idx - i * 36864;
  int h = rem / 9216;
  int rem2 = rem - h * 9216;
  int c = rem2 / 96;
  int r = rem2 - c * 96;
  int rr = r - i; if (rr < 0) rr += 96;
  const float* post = (h == 0) ? post1 : (h == 1) ? post2 : (h == 2) ? post3 : post4;
  const float* K2   = (h == 0) ? ck1   : (h == 1) ? sk1   : (h == 2) ? ck3   : sk4;
  Qrot[idx] = f2bf_bits(post[rr] * K2[rr * 96 + c]);
}

// ---------------------------------------------------------------------------
// stage 1: one WG per (b, group of 6 i).
//   U_{h,i}[c,k''] = sum_{r''} Qrot_i[r'',c] * X[r'',k'']      (MFMA)
//   polar[b,i,c]   = sum_h sum_{k''} U[c,k''] * Pf_h[(k''-i)%96, c]
// X staged ONCE per (b,phase) into LDS transposed (XdT[k''][r'']) — no
// per-i re-gather. 4 waves: w&1 -> c-half, w>>1 -> helper within phase.
// 2-pass nt-split keeps acc at 36 VGPRs (<=128 total -> 4 WG/CU).
// ---------------------------------------------------------------------------
__global__ __launch_bounds__(256, 4) void k_stage1(
    const float* __restrict__ inputs,          // [64][2][9216] f32
    const unsigned short* __restrict__ Qrot,   // [96][4][96][96] bf16
    const float* __restrict__ Pf,              // [4][96][96] f32
    unsigned short* __restrict__ polar)        // [64][9216] bf16
{
  __shared__ unsigned short XdT[96][104];      // XdT[k''][r''] = bf16(X[r''][k''])
  __shared__ float pacc[6][96];

  int blk = blockIdx.x;                        // 1024 = 64 b * 16 groups
  int b = blk >> 4;
  int g = blk & 15;
  int i0 = g * 6;
  int tid = threadIdx.x;
  int lane = tid & 63;
  int w = tid >> 6;
  int l15 = lane & 15;
  int lg = lane >> 4;
  int kg = lg * 8;
  int hsel = w >> 1;
  int chalf = (w & 1) * 48;

  for (int e = tid; e < 576; e += 256) ((float*)pacc)[e] = 0.f;

  const float* srcB = inputs + (size_t)b * 18432;

  for (int ph = 0; ph < 2; ++ph) {
    const float* src = srcB + ph * 9216;       // ph0: R, ph1: I
    __syncthreads();                           // XdT reusable; pacc init visible
    for (int e = tid; e < 9216; e += 256) {
      int r = e / 96;
      int j = e - r * 96;
      XdT[j][r] = f2bf_bits(src[e]);           // coalesced global read
    }
    __syncthreads();

    int h = ph * 2 + hsel;
    const unsigned short* QrH = Qrot + h * 9216;
    const float* PfH = Pf + h * 9216;

    for (int ii = 0; ii < 6; ++ii) {
      int i = i0 + ii;
      const unsigned short* QrI = QrH + (size_t)i * 36864;
      floatx4 svc[3];
      svc[0] = 0.f; svc[1] = 0.f; svc[2] = 0.f;

#pragma unroll
      for (int pass = 0; pass < 2; ++pass) {
        floatx4 acc[3][3];
#pragma unroll
        for (int ct = 0; ct < 3; ++ct)
#pragma unroll
          for (int ntl = 0; ntl < 3; ++ntl)
            acc[ct][ntl] = 0.f;

#pragma unroll
        for (int ks = 0; ks < 3; ++ks) {
          bf16x8 afr[3];
#pragma unroll
          for (int ct = 0; ct < 3; ++ct)
            afr[ct] = *reinterpret_cast<const bf16x8*>(
                QrI + (chalf + ct * 16 + l15) * 96 + ks * 32 + kg);
#pragma unroll
          for (int ntl = 0; ntl < 3; ++ntl) {
            int nt = pass * 3 + ntl;
            bf16x8 bfr = *reinterpret_cast<const bf16x8*>(
                &XdT[nt * 16 + l15][ks * 32 + kg]);
#pragma unroll
            for (int ct = 0; ct < 3; ++ct)
              acc[ct][ntl] = __builtin_amdgcn_mfma_f32_16x16x32_bf16(
                  afr[ct], bfr, acc[ct][ntl], 0, 0, 0);
          }
        }

        // elementwise P-weighted partial reduce over this pass's k''-tiles
#pragma unroll
        for (int ct = 0; ct < 3; ++ct) {
          int c0 = chalf + ct * 16 + lg * 4;
#pragma unroll
          for (int ntl = 0; ntl < 3; ++ntl) {
            int nt = pass * 3 + ntl;
            int krot = nt * 16 + l15 - i; if (krot < 0) krot += 96;
            floatx4 pw = *reinterpret_cast<const floatx4*>(PfH + krot * 96 + c0);
            svc[ct] += pw * acc[ct][ntl];
          }
        }
      }

      // sum over the 16 k''-residues (l15) and accumulate
#pragma unroll
      for (int ct = 0; ct < 3; ++ct) {
        int c0 = chalf + ct * 16 + lg * 4;
#pragma unroll
        for (int q = 0; q < 4; ++q) {
          float v = svc[ct][q];
          v += __shfl_xor(v, 1);
          v += __shfl_xor(v, 2);
          v += __shfl_xor(v, 4);
          v += __shfl_xor(v, 8);
          if (l15 == 0) atomicAdd(&pacc[ii][c0 + q], v);
        }
      }
    }
  }

  __syncthreads();
  for (int e = tid; e < 576; e += 256) {
    int ii = e / 96;
    int c = e - ii * 96;
    polar[(size_t)b * 9216 + (i0 + ii) * 96 + c] = f2bf_bits(pacc[ii][c]);
  }
}

// ---------------------------------------------------------------------------
// stage 2: part[sp][b][m] = sum_{n in split sp} polar[b][n] * cart[m][n]
// grid (144 m-tiles of 64, 16 K-splits of 576) = 2304 WGs = 9.0/CU exact.
// cart converted f32->bf16 in-register; coalesced 128B row chunks.
// ---------------------------------------------------------------------------
__global__ __launch_bounds__(256) void k_stage2(
    const unsigned short* __restrict__ polar,  // [64][9216] bf16
    const float* __restrict__ cart,            // [9216][9216] f32
    float* __restrict__ part)                  // [16][64][9216] f32
{
  int tid = threadIdx.x;
  int lane = tid & 63;
  int w = tid >> 6;
  int l15 = lane & 15;
  int m = blockIdx.x * 64 + w * 16 + l15;
  int kg = (lane >> 4) * 8;
  int k0 = blockIdx.y * 576;

  floatx4 acc[4] = {};

  const float* crow = cart + (size_t)m * 9216 + k0 + kg;
  const unsigned short* prow = polar + (size_t)l15 * 9216 + k0 + kg;

  for (int ks = 0; ks < 18; ++ks) {
    floatx4 c0 = *reinterpret_cast<const floatx4*>(crow);
    floatx4 c1 = *reinterpret_cast<const floatx4*>(crow + 4);
    bf16x8 bf;
    bf[0] = (__bf16)c0[0]; bf[1] = (__bf16)c0[1]; bf[2] = (__bf16)c0[2]; bf[3] = (__bf16)c0[3];
    bf[4] = (__bf16)c1[0]; bf[5] = (__bf16)c1[1]; bf[6] = (__bf16)c1[2]; bf[7] = (__bf16)c1[3];
#pragma unroll
    for (int bt = 0; bt < 4; ++bt) {
      bf16x8 af = *reinterpret_cast<const bf16x8*>(prow + bt * 147456);
      acc[bt] = __builtin_amdgcn_mfma_f32_16x16x32_bf16(af, bf, acc[bt], 0, 0, 0);
    }
    crow += 32;
    prow += 32;
  }

  int rg = (lane >> 4) * 4;
#pragma unroll
  for (int bt = 0; bt < 4; ++bt) {
    int b0 = bt * 16 + rg;
#pragma unroll
    for (int q = 0; q < 4; ++q) {
      part[((size_t)blockIdx.y * 64 + b0 + q) * 9216 + m] = acc[bt][q];
    }
  }
}

// ---------------------------------------------------------------------------
// reduce the 16 K-split partials into d_out (f32)
// ---------------------------------------------------------------------------
__global__ __launch_bounds__(256) void k_reduce(
    const float* __restrict__ part, float* __restrict__ out)
{
  int idx = blockIdx.x * 256 + threadIdx.x;    // exactly 589824 threads
  float s = 0.f;
#pragma unroll
  for (int sp = 0; sp < 16; ++sp) s += part[(size_t)sp * 589824 + idx];
  out[idx] = s;
}

// ---------------------------------------------------------------------------
extern "C" void kernel_launch(void* const* d_in, const int* in_sizes, int n_in,
                              void* d_out, int out_size, void* d_ws, size_t ws_size,
                              hipStream_t stream) {
  const float* inputs = (const float*)d_in[0];
  const float* cart   = (const float*)d_in[1];

  char* ws = (char*)d_ws;
  float*          Pf    = (float*)(ws + 0);                 //   147,456 B
  unsigned short* Qrot  = (unsigned short*)(ws + 147456);   // 7,077,888 B
  unsigned short* polar = (unsigned short*)(ws + 7225344);  // 1,179,648 B
  float*          part  = (float*)(ws + 8404992);           // 37,748,736 B (total ~46.2 MB)

  k_prep_p<<<144, 256, 0, stream>>>(
      (const float*)d_in[2],  (const float*)d_in[3],  (const float*)d_in[4],  (const float*)d_in[5],
      (const float*)d_in[12], (const float*)d_in[13], (const float*)d_in[15], (const float*)d_in[16],
      Pf);

  k_prep_q<<<13824, 256, 0, stream>>>(
      (const float*)d_in[6],  (const float*)d_in[7],  (const float*)d_in[8],  (const float*)d_in[9],
      (const float*)d_in[10], (const float*)d_in[11], (const float*)d_in[14], (const float*)d_in[17],
      Qrot);

  k_stage1<<<1024, 256, 0, stream>>>(inputs, Qrot, Pf, polar);

  k_stage2<<<dim3(144, 16), 256, 0, stream>>>(polar, cart, part);

  k_reduce<<<2304, 256, 0, stream>>>(part, (float*)d_out);
}

// Round 4
// 669.914 us; speedup vs baseline: 1.3016x; 1.3016x over previous
//
#include <hip/hip_runtime.h>

typedef __bf16 bf16x8 __attribute__((ext_vector_type(8)));
typedef float floatx4 __attribute__((ext_vector_type(4)));
typedef unsigned int u32;
typedef unsigned short u16;

__device__ __forceinline__ u16 f2bf_bits(float f) {
  __bf16 h = (__bf16)f;
  return __builtin_bit_cast(u16, h);
}

// ---------------------------------------------------------------------------
// prep: Pf[h][k][c] = pre_h[k]  * K1_h[k][c]   (f32, c contiguous)
//       Qbf[h][c][r] = post_h[r] * K2_h[r][c]  (bf16, r contiguous = transposed)
// h: 0->(pre1,post1,K1=ck2,K2=ck1) 1->(pre2,post2,sk2,sk1)
//    2->(pre3,post3,sk3,ck3)       3->(pre4,post4,ck4,sk4)
// ---------------------------------------------------------------------------
__global__ __launch_bounds__(256) void k_prep(
    const float* __restrict__ pre1, const float* __restrict__ pre2,
    const float* __restrict__ pre3, const float* __restrict__ pre4,
    const float* __restrict__ post1, const float* __restrict__ post2,
    const float* __restrict__ post3, const float* __restrict__ post4,
    const float* __restrict__ ck1, const float* __restrict__ sk1,
    const float* __restrict__ ck2, const float* __restrict__ sk2,
    const float* __restrict__ ck3, const float* __restrict__ sk3,
    const float* __restrict__ ck4, const float* __restrict__ sk4,
    float* __restrict__ Pf, u16* __restrict__ Qbf)
{
  int idx = blockIdx.x * 256 + threadIdx.x;        // 4*9216 threads exact
  int h = idx / 9216;
  int rem = idx - h * 9216;
  int y = rem / 96;                                // k for Pf, r for Qbf
  int z = rem - y * 96;                            // c
  const float* pre  = (h == 0) ? pre1 : (h == 1) ? pre2 : (h == 2) ? pre3 : pre4;
  const float* post = (h == 0) ? post1 : (h == 1) ? post2 : (h == 2) ? post3 : post4;
  const float* K1   = (h == 0) ? ck2 : (h == 1) ? sk2 : (h == 2) ? sk3 : ck4;
  const float* K2   = (h == 0) ? ck1 : (h == 1) ? sk1 : (h == 2) ? ck3 : sk4;
  Pf[idx] = pre[y] * K1[y * 96 + z];
  Qbf[h * 9216 + z * 96 + y] = f2bf_bits(post[y] * K2[y * 96 + z]);
}

// ---------------------------------------------------------------------------
// register funnel-shift of a 16-element bf16 window by IR elements (0..7)
// ---------------------------------------------------------------------------
template<int IR>
__device__ __forceinline__ uint4 shift_frag(uint4 lo, uint4 hi) {
  u32 s[8] = {lo.x, lo.y, lo.z, lo.w, hi.x, hi.y, hi.z, hi.w};
  uint4 o;
  constexpr int m = IR >> 1;
  if constexpr ((IR & 1) == 0) {
    o.x = s[m + 0]; o.y = s[m + 1]; o.z = s[m + 2]; o.w = s[m + 3];
  } else {
    o.x = (s[m + 0] >> 16) | (s[m + 1] << 16);
    o.y = (s[m + 1] >> 16) | (s[m + 2] << 16);
    o.z = (s[m + 2] >> 16) | (s[m + 3] << 16);
    o.w = (s[m + 3] >> 16) | (s[m + 4] << 16);
  }
  return o;
}

__device__ __forceinline__ void shift3(const uint4* lo, const uint4* hi, int ir, uint4* out) {
  switch (ir) {
    case 0: out[0]=shift_frag<0>(lo[0],hi[0]); out[1]=shift_frag<0>(lo[1],hi[1]); out[2]=shift_frag<0>(lo[2],hi[2]); break;
    case 1: out[0]=shift_frag<1>(lo[0],hi[0]); out[1]=shift_frag<1>(lo[1],hi[1]); out[2]=shift_frag<1>(lo[2],hi[2]); break;
    case 2: out[0]=shift_frag<2>(lo[0],hi[0]); out[1]=shift_frag<2>(lo[1],hi[1]); out[2]=shift_frag<2>(lo[2],hi[2]); break;
    case 3: out[0]=shift_frag<3>(lo[0],hi[0]); out[1]=shift_frag<3>(lo[1],hi[1]); out[2]=shift_frag<3>(lo[2],hi[2]); break;
    case 4: out[0]=shift_frag<4>(lo[0],hi[0]); out[1]=shift_frag<4>(lo[1],hi[1]); out[2]=shift_frag<4>(lo[2],hi[2]); break;
    case 5: out[0]=shift_frag<5>(lo[0],hi[0]); out[1]=shift_frag<5>(lo[1],hi[1]); out[2]=shift_frag<5>(lo[2],hi[2]); break;
    case 6: out[0]=shift_frag<6>(lo[0],hi[0]); out[1]=shift_frag<6>(lo[1],hi[1]); out[2]=shift_frag<6>(lo[2],hi[2]); break;
    default:out[0]=shift_frag<7>(lo[0],hi[0]); out[1]=shift_frag<7>(lo[1],hi[1]); out[2]=shift_frag<7>(lo[2],hi[2]); break;
  }
}

// ---------------------------------------------------------------------------
// stage 1: one WG per (b, group of 6 i).
//   polar[b,i,c] = sum_h sum_k'' Pf_h[(k''-i)%96,c] * U_h[c,k''],
//   U_h[c,k''] = sum_r Q_h[r,c] * X[(r+i)%96, k'']   (MFMA, Q in regs,
// rotation as shifted LDS window), then elementwise P-weighted reduce.
// Xd[k''][col c] = bf16( X[(W+c)%96][k''] ), W = 8*(i0>>3), cols 0..111,
// chunk-XOR swizzled (T2). 4 waves = (c-half) x (k''-half); each wave's
// X-frags serve BOTH h of the phase (halves LDS reads).
// ---------------------------------------------------------------------------
__global__ __launch_bounds__(256, 2) void k_stage1(
    const float* __restrict__ inputs,          // [64][2][9216] f32
    const u16* __restrict__ Qbf,               // [4][96][96] bf16 (c-major)
    const float* __restrict__ Pf,              // [4][96][96] f32  (k-major)
    u16* __restrict__ polar)                   // [64][9216] bf16
{
  __shared__ __align__(16) u16 Xd[96 * 128];   // 24,576 B
  __shared__ float pacc[6][96];                // 2,304 B

  int blk = blockIdx.x;                        // 1024 = 64 b * 16 groups
  int b = blk >> 4;
  int i0 = (blk & 15) * 6;
  int W = 8 * (i0 >> 3);
  int tid = threadIdx.x;
  int lane = tid & 63;
  int w = tid >> 6;
  int l15 = lane & 15;
  int lg = lane >> 4;
  int chalf = w >> 1;                          // c-half: c in [chalf*48, +48)
  int nhalf = w & 1;                           // k''-half: nt in {nhalf*3+0..2}

  for (int e = tid; e < 576; e += 256) ((float*)pacc)[e] = 0.f;

  for (int ph = 0; ph < 2; ++ph) {
    // ---- stage X (transposed, windowed, swizzled) ----
    __syncthreads();                           // Xd free; pacc init visible
    const float4* src4 = reinterpret_cast<const float4*>(
        inputs + (size_t)b * 18432 + ph * 9216);
    for (int e4 = tid; e4 < 2304; e4 += 256) {
      int rX = e4 / 24;                        // X row (r-contraction axis)
      int kq = e4 - rX * 24;                   // group of 4 k''
      float4 v = src4[e4];
      int c = rX - W; if (c < 0) c += 96;
      int ch = c >> 3, cs = c & 7;
      int c2 = c + 96;
      int ch2 = c2 >> 3, cs2 = c2 & 7;
      bool dup = (c < 16);
#pragma unroll
      for (int j = 0; j < 4; ++j) {
        int row = kq * 4 + j;
        u16 bv = f2bf_bits(((const float*)&v)[j]);
        int sw = row & 7;
        Xd[row * 128 + ((ch ^ sw) << 3) + cs] = bv;
        if (dup) Xd[row * 128 + ((ch2 ^ sw) << 3) + cs2] = bv;
      }
    }
    __syncthreads();

    // ---- Q fragments for this phase (A-operand, i-independent) ----
    bf16x8 Qf[2][3][3];                        // [h2][ct][ks]
#pragma unroll
    for (int h2 = 0; h2 < 2; ++h2)
#pragma unroll
      for (int ct = 0; ct < 3; ++ct)
#pragma unroll
        for (int ks = 0; ks < 3; ++ks)
          Qf[h2][ct][ks] = *reinterpret_cast<const bf16x8*>(
              Qbf + (ph * 2 + h2) * 9216 +
              (chalf * 48 + ct * 16 + l15) * 96 + ks * 32 + lg * 8);

    for (int ii = 0; ii < 6; ++ii) {
      int i = i0 + ii;
      int s = i - W;                           // 0..12
      int ia = s >> 3, ir = s & 7;
      floatx4 svc[3];
      svc[0] = 0.f; svc[1] = 0.f; svc[2] = 0.f;

      for (int ntl = 0; ntl < 3; ++ntl) {
        int nt = nhalf * 3 + ntl;
        int row = nt * 16 + l15;               // k'' row of Xd
        const u16* xr = &Xd[row * 128];
        int sw = row & 7;
        uint4 lo[3], hi[3];
#pragma unroll
        for (int ks = 0; ks < 3; ++ks) {
          int chE = ks * 4 + lg + ia;          // aligned 8-el chunk index
          lo[ks] = *reinterpret_cast<const uint4*>(xr + (((chE    ) ^ sw) << 3));
          hi[ks] = *reinterpret_cast<const uint4*>(xr + (((chE + 1) ^ sw) << 3));
        }
        uint4 Bu[3];
        shift3(lo, hi, ir, Bu);

        floatx4 acc[2][3];
#pragma unroll
        for (int h2 = 0; h2 < 2; ++h2)
#pragma unroll
          for (int ct = 0; ct < 3; ++ct) acc[h2][ct] = 0.f;

#pragma unroll
        for (int ks = 0; ks < 3; ++ks) {
          bf16x8 bb = __builtin_bit_cast(bf16x8, Bu[ks]);
#pragma unroll
          for (int h2 = 0; h2 < 2; ++h2)
#pragma unroll
            for (int ct = 0; ct < 3; ++ct)
              acc[h2][ct] = __builtin_amdgcn_mfma_f32_16x16x32_bf16(
                  Qf[h2][ct][ks], bb, acc[h2][ct], 0, 0, 0);
        }

        // P-weighted elementwise reduce over this k''-tile
        int krot = nt * 16 + l15 - i; if (krot < 0) krot += 96;
#pragma unroll
        for (int h2 = 0; h2 < 2; ++h2) {
          const float* PfH = Pf + (ph * 2 + h2) * 9216 + krot * 96 + chalf * 48;
#pragma unroll
          for (int ct = 0; ct < 3; ++ct) {
            floatx4 pw = *reinterpret_cast<const floatx4*>(PfH + ct * 16 + lg * 4);
            svc[ct] += pw * acc[h2][ct];
          }
        }
      }

      // sum over 16 k''-residues (l15 tree) and accumulate into pacc
#pragma unroll
      for (int ct = 0; ct < 3; ++ct) {
        int c0 = chalf * 48 + ct * 16 + lg * 4;
#pragma unroll
        for (int q = 0; q < 4; ++q) {
          float v = svc[ct][q];
          v += __shfl_xor(v, 1);
          v += __shfl_xor(v, 2);
          v += __shfl_xor(v, 4);
          v += __shfl_xor(v, 8);
          if (l15 == 0) atomicAdd(&pacc[ii][c0 + q], v);
        }
      }
    }
  }

  __syncthreads();
  for (int e = tid; e < 576; e += 256) {
    int ii = e / 96;
    int c = e - ii * 96;
    polar[(size_t)b * 9216 + (i0 + ii) * 96 + c] = f2bf_bits(pacc[ii][c]);
  }
}

// ---------------------------------------------------------------------------
// stage 2: part[sp][b][m] = sum_{n in split sp} polar[b][n] * cart[m][n]
// grid (144 m-tiles of 64, 16 K-splits of 576) = 2304 WGs = 9.0/CU exact.
// ---------------------------------------------------------------------------
__global__ __launch_bounds__(256) void k_stage2(
    const u16* __restrict__ polar,             // [64][9216] bf16
    const float* __restrict__ cart,            // [9216][9216] f32
    float* __restrict__ part)                  // [16][64][9216] f32
{
  int tid = threadIdx.x;
  int lane = tid & 63;
  int w = tid >> 6;
  int l15 = lane & 15;
  int m = blockIdx.x * 64 + w * 16 + l15;
  int kg = (lane >> 4) * 8;
  int k0 = blockIdx.y * 576;

  floatx4 acc[4] = {};

  const float* crow = cart + (size_t)m * 9216 + k0 + kg;
  const u16* prow = polar + (size_t)l15 * 9216 + k0 + kg;

  for (int ks = 0; ks < 18; ++ks) {
    floatx4 c0 = *reinterpret_cast<const floatx4*>(crow);
    floatx4 c1 = *reinterpret_cast<const floatx4*>(crow + 4);
    bf16x8 bf;
    bf[0] = (__bf16)c0[0]; bf[1] = (__bf16)c0[1]; bf[2] = (__bf16)c0[2]; bf[3] = (__bf16)c0[3];
    bf[4] = (__bf16)c1[0]; bf[5] = (__bf16)c1[1]; bf[6] = (__bf16)c1[2]; bf[7] = (__bf16)c1[3];
#pragma unroll
    for (int bt = 0; bt < 4; ++bt) {
      bf16x8 af = *reinterpret_cast<const bf16x8*>(prow + bt * 147456);
      acc[bt] = __builtin_amdgcn_mfma_f32_16x16x32_bf16(af, bf, acc[bt], 0, 0, 0);
    }
    crow += 32;
    prow += 32;
  }

  int rg = (lane >> 4) * 4;
#pragma unroll
  for (int bt = 0; bt < 4; ++bt) {
    int b0 = bt * 16 + rg;
#pragma unroll
    for (int q = 0; q < 4; ++q) {
      part[((size_t)blockIdx.y * 64 + b0 + q) * 9216 + m] = acc[bt][q];
    }
  }
}

// ---------------------------------------------------------------------------
// reduce the 16 K-split partials into d_out (f32)
// ---------------------------------------------------------------------------
__global__ __launch_bounds__(256) void k_reduce(
    const float* __restrict__ part, float* __restrict__ out)
{
  int idx = blockIdx.x * 256 + threadIdx.x;    // exactly 589824 threads
  float s = 0.f;
#pragma unroll
  for (int sp = 0; sp < 16; ++sp) s += part[(size_t)sp * 589824 + idx];
  out[idx] = s;
}

// ---------------------------------------------------------------------------
extern "C" void kernel_launch(void* const* d_in, const int* in_sizes, int n_in,
                              void* d_out, int out_size, void* d_ws, size_t ws_size,
                              hipStream_t stream) {
  const float* inputs = (const float*)d_in[0];
  const float* cart   = (const float*)d_in[1];

  char* ws = (char*)d_ws;
  float* Pf   = (float*)(ws + 0);              //   147,456 B
  u16*   Qbf  = (u16*)(ws + 147456);           //    73,728 B
  u16*   polar= (u16*)(ws + 221184);           // 1,179,648 B
  float* part = (float*)(ws + 1400832);        // 37,748,736 B (total ~39.1 MB)

  k_prep<<<144, 256, 0, stream>>>(
      (const float*)d_in[2],  (const float*)d_in[3],  (const float*)d_in[4],  (const float*)d_in[5],
      (const float*)d_in[6],  (const float*)d_in[7],  (const float*)d_in[8],  (const float*)d_in[9],
      (const float*)d_in[10], (const float*)d_in[11], (const float*)d_in[12], (const float*)d_in[13],
      (const float*)d_in[14], (const float*)d_in[15], (const float*)d_in[16], (const float*)d_in[17],
      Pf, Qbf);

  k_stage1<<<1024, 256, 0, stream>>>(inputs, Qbf, Pf, polar);

  k_stage2<<<dim3(144, 16), 256, 0, stream>>>(polar, cart, part);

  k_reduce<<<2304, 256, 0, stream>>>(part, (float*)d_out);
}

// Round 5
// 659.272 us; speedup vs baseline: 1.3226x; 1.0161x over previous
//
#include <hip/hip_runtime.h>

typedef __bf16 bf16x8 __attribute__((ext_vector_type(8)));
typedef float floatx4 __attribute__((ext_vector_type(4)));
typedef unsigned int u32;
typedef unsigned short u16;

__device__ __forceinline__ u16 f2bf_bits(float f) {
  __bf16 h = (__bf16)f;
  return __builtin_bit_cast(u16, h);
}

// pin a 16B value in VGPRs (defeat restrict-based load re-sinking)
__device__ __forceinline__ void keep4(uint4& v) {
  asm("" : "+v"(v.x), "+v"(v.y), "+v"(v.z), "+v"(v.w));
}

// ---------------------------------------------------------------------------
// prep: Pf[h][k][c] = pre_h[k]  * K1_h[k][c]   (f32, c contiguous)
//       Qbf[h][c][r] = post_h[r] * K2_h[r][c]  (bf16, r contiguous)
// h: 0->(pre1,post1,K1=ck2,K2=ck1) 1->(pre2,post2,sk2,sk1)
//    2->(pre3,post3,sk3,ck3)       3->(pre4,post4,ck4,sk4)
// ---------------------------------------------------------------------------
__global__ __launch_bounds__(256) void k_prep(
    const float* __restrict__ pre1, const float* __restrict__ pre2,
    const float* __restrict__ pre3, const float* __restrict__ pre4,
    const float* __restrict__ post1, const float* __restrict__ post2,
    const float* __restrict__ post3, const float* __restrict__ post4,
    const float* __restrict__ ck1, const float* __restrict__ sk1,
    const float* __restrict__ ck2, const float* __restrict__ sk2,
    const float* __restrict__ ck3, const float* __restrict__ sk3,
    const float* __restrict__ ck4, const float* __restrict__ sk4,
    float* __restrict__ Pf, u16* __restrict__ Qbf)
{
  int idx = blockIdx.x * 256 + threadIdx.x;        // 4*9216 threads exact
  int h = idx / 9216;
  int rem = idx - h * 9216;
  int y = rem / 96;                                // k for Pf, r for Qbf
  int z = rem - y * 96;                            // c
  const float* pre  = (h == 0) ? pre1 : (h == 1) ? pre2 : (h == 2) ? pre3 : pre4;
  const float* post = (h == 0) ? post1 : (h == 1) ? post2 : (h == 2) ? post3 : post4;
  const float* K1   = (h == 0) ? ck2 : (h == 1) ? sk2 : (h == 2) ? sk3 : ck4;
  const float* K2   = (h == 0) ? ck1 : (h == 1) ? sk1 : (h == 2) ? ck3 : sk4;
  Pf[idx] = pre[y] * K1[y * 96 + z];
  Qbf[h * 9216 + z * 96 + y] = f2bf_bits(post[y] * K2[y * 96 + z]);
}

// ---------------------------------------------------------------------------
// register funnel-shift of a 16-element bf16 window by IR elements (0..7)
// ---------------------------------------------------------------------------
template<int IR>
__device__ __forceinline__ uint4 shift_frag(uint4 lo, uint4 hi) {
  u32 s[8] = {lo.x, lo.y, lo.z, lo.w, hi.x, hi.y, hi.z, hi.w};
  uint4 o;
  constexpr int m = IR >> 1;
  if constexpr ((IR & 1) == 0) {
    o.x = s[m + 0]; o.y = s[m + 1]; o.z = s[m + 2]; o.w = s[m + 3];
  } else {
    o.x = (s[m + 0] >> 16) | (s[m + 1] << 16);
    o.y = (s[m + 1] >> 16) | (s[m + 2] << 16);
    o.z = (s[m + 2] >> 16) | (s[m + 3] << 16);
    o.w = (s[m + 3] >> 16) | (s[m + 4] << 16);
  }
  return o;
}

__device__ __forceinline__ void shift3(const uint4* lo, const uint4* hi, int ir, uint4* out) {
  switch (ir) {
    case 0: out[0]=shift_frag<0>(lo[0],hi[0]); out[1]=shift_frag<0>(lo[1],hi[1]); out[2]=shift_frag<0>(lo[2],hi[2]); break;
    case 1: out[0]=shift_frag<1>(lo[0],hi[0]); out[1]=shift_frag<1>(lo[1],hi[1]); out[2]=shift_frag<1>(lo[2],hi[2]); break;
    case 2: out[0]=shift_frag<2>(lo[0],hi[0]); out[1]=shift_frag<2>(lo[1],hi[1]); out[2]=shift_frag<2>(lo[2],hi[2]); break;
    case 3: out[0]=shift_frag<3>(lo[0],hi[0]); out[1]=shift_frag<3>(lo[1],hi[1]); out[2]=shift_frag<3>(lo[2],hi[2]); break;
    case 4: out[0]=shift_frag<4>(lo[0],hi[0]); out[1]=shift_frag<4>(lo[1],hi[1]); out[2]=shift_frag<4>(lo[2],hi[2]); break;
    case 5: out[0]=shift_frag<5>(lo[0],hi[0]); out[1]=shift_frag<5>(lo[1],hi[1]); out[2]=shift_frag<5>(lo[2],hi[2]); break;
    case 6: out[0]=shift_frag<6>(lo[0],hi[0]); out[1]=shift_frag<6>(lo[1],hi[1]); out[2]=shift_frag<6>(lo[2],hi[2]); break;
    default:out[0]=shift_frag<7>(lo[0],hi[0]); out[1]=shift_frag<7>(lo[1],hi[1]); out[2]=shift_frag<7>(lo[2],hi[2]); break;
  }
}

// ---------------------------------------------------------------------------
// stage 1 (v3): one WG per (b, group of 6 i).
//   polar[b,i,c] = sum_h sum_k Pf_h[k,c] * D_i[k,c],
//   D_i[k,c] = sum_r X[(r+i)%96,(k+i)%96] * Q_h[r,c]     (MFMA: A=Xrot, B=Q)
// Both rotations live on the X side: k-rot = per-lane LDS row ring,
// r-rot = col-window + register funnel shift. Pf weights are therefore
// i-independent (hoisted, lane-coalesced); P-contraction is in-lane fma;
// cross-lane reduce deferred to 2 shfl_xor per output at kernel end.
// Xd[kk][cc] = bf16( X[(W+cc)%96, kk] ), W = 8*(i0>>3), cc 0..111,
// chunk-XOR swizzled. 4 waves = (c-half) x (k-tile-half).
// ---------------------------------------------------------------------------
__global__ __launch_bounds__(256, 2) void k_stage1(
    const float* __restrict__ inputs,          // [64][2][9216] f32
    const u16* __restrict__ Qbf,               // [4][96][96] bf16 (c-major)
    const float* __restrict__ Pf,              // [4][96][96] f32  (k-major)
    u16* __restrict__ polar)                   // [64][9216] bf16
{
  __shared__ __align__(16) u16 Xd[96 * 128];   // 24,576 B
  __shared__ float pacc[2][6][96];             //  4,608 B

  int blk = blockIdx.x;                        // 1024 = 64 b * 16 groups
  int b = blk >> 4;
  int i0 = (blk & 15) * 6;
  int W = 8 * (i0 >> 3);
  int s0 = i0 - W;                             // 0..11 window offset base
  int tid = threadIdx.x;
  int lane = tid & 63;
  int w = tid >> 6;
  int l15 = lane & 15;
  int lg = lane >> 4;
  int chalf = w >> 1;                          // c in [chalf*48, +48)
  int nhalf = w & 1;                           // k-tiles {nhalf*3+0..2}

  float svc[6][3];                             // [ii][ct] scalar per lane
#pragma unroll
  for (int ii = 0; ii < 6; ++ii)
#pragma unroll
    for (int ct = 0; ct < 3; ++ct) svc[ii][ct] = 0.f;

  for (int ph = 0; ph < 2; ++ph) {
    // ---- stage X (transposed, windowed, swizzled) ----
    __syncthreads();                           // Xd free to overwrite
    const float4* src4 = reinterpret_cast<const float4*>(
        inputs + (size_t)b * 18432 + ph * 9216);
    for (int e4 = tid; e4 < 2304; e4 += 256) {
      int rX = e4 / 24;                        // X axis-1 (r-dim) -> cols
      int kq = e4 - rX * 24;                   // group of 4 axis-2 (k-dim)
      float4 v = src4[e4];
      int c = rX - W; if (c < 0) c += 96;
      int ch = c >> 3, cs = c & 7;
      int c2 = c + 96;
      int ch2 = c2 >> 3, cs2 = c2 & 7;
      bool dup = (c < 16);
#pragma unroll
      for (int j = 0; j < 4; ++j) {
        int row = kq * 4 + j;
        u16 bv = f2bf_bits(((const float*)&v)[j]);
        int sw = row & 7;
        Xd[row * 128 + ((ch ^ sw) << 3) + cs] = bv;
        if (dup) Xd[row * 128 + ((ch2 ^ sw) << 3) + cs2] = bv;
      }
    }
    __syncthreads();

    // ---- Q fragments (B-operand, i-independent), pinned in VGPRs ----
    bf16x8 Qf[2][3][3];                        // [h2][ct][ks]
#pragma unroll
    for (int h2 = 0; h2 < 2; ++h2)
#pragma unroll
      for (int ct = 0; ct < 3; ++ct)
#pragma unroll
        for (int ks = 0; ks < 3; ++ks) {
          uint4 t = *reinterpret_cast<const uint4*>(
              Qbf + (ph * 2 + h2) * 9216 +
              (chalf * 48 + ct * 16 + l15) * 96 + ks * 32 + lg * 8);
          keep4(t);
          Qf[h2][ct][ks] = __builtin_bit_cast(bf16x8, t);
        }

    for (int ntl = 0; ntl < 3; ++ntl) {
      int nt = nhalf * 3 + ntl;
      // ---- Pf weights: i-independent, lane-coalesced, hoisted over ii ----
      float pw[2][3][4];
#pragma unroll
      for (int h2 = 0; h2 < 2; ++h2)
#pragma unroll
        for (int ct = 0; ct < 3; ++ct)
#pragma unroll
          for (int q = 0; q < 4; ++q)
            pw[h2][ct][q] = Pf[(ph * 2 + h2) * 9216 +
                               (nt * 16 + lg * 4 + q) * 96 +
                               chalf * 48 + ct * 16 + l15];
      int rowb = nt * 16 + l15 + i0;

#pragma unroll
      for (int ii = 0; ii < 6; ++ii) {
        int s = s0 + ii;
        int ia = s >> 3, ir = s & 7;
        int rowIdx = rowb + ii; if (rowIdx >= 96) rowIdx -= 96;  // k-ring
        const u16* xr = &Xd[rowIdx * 128];
        int sw = rowIdx & 7;
        uint4 lo[3], hi[3];
#pragma unroll
        for (int ks = 0; ks < 3; ++ks) {
          int chE = ks * 4 + lg + ia;
          lo[ks] = *reinterpret_cast<const uint4*>(xr + (((chE    ) ^ sw) << 3));
          hi[ks] = *reinterpret_cast<const uint4*>(xr + (((chE + 1) ^ sw) << 3));
        }
        uint4 Bu[3];
        shift3(lo, hi, ir, Bu);

        floatx4 acc[2][3];
#pragma unroll
        for (int h2 = 0; h2 < 2; ++h2)
#pragma unroll
          for (int ct = 0; ct < 3; ++ct) acc[h2][ct] = 0.f;

#pragma unroll
        for (int ks = 0; ks < 3; ++ks) {
          bf16x8 aa = __builtin_bit_cast(bf16x8, Bu[ks]);
#pragma unroll
          for (int h2 = 0; h2 < 2; ++h2)
#pragma unroll
            for (int ct = 0; ct < 3; ++ct)
              acc[h2][ct] = __builtin_amdgcn_mfma_f32_16x16x32_bf16(
                  aa, Qf[h2][ct][ks], acc[h2][ct], 0, 0, 0);
        }

        // in-lane P-weighted contraction over this k-tile's 4 reg-rows
#pragma unroll
        for (int h2 = 0; h2 < 2; ++h2)
#pragma unroll
          for (int ct = 0; ct < 3; ++ct)
            svc[ii][ct] += pw[h2][ct][0] * acc[h2][ct][0]
                         + pw[h2][ct][1] * acc[h2][ct][1]
                         + pw[h2][ct][2] * acc[h2][ct][2]
                         + pw[h2][ct][3] * acc[h2][ct][3];
      }
    }
  }

  // ---- deferred cross-lane reduce (lg groups) + disjoint pacc writes ----
#pragma unroll
  for (int ii = 0; ii < 6; ++ii)
#pragma unroll
    for (int ct = 0; ct < 3; ++ct) {
      float v = svc[ii][ct];
      v += __shfl_xor(v, 16);
      v += __shfl_xor(v, 32);
      if (lg == 0) pacc[nhalf][ii][chalf * 48 + ct * 16 + l15] = v;
    }

  __syncthreads();
  for (int e = tid; e < 576; e += 256) {
    int ii = e / 96;
    int c = e - ii * 96;
    polar[(size_t)b * 9216 + (i0 + ii) * 96 + c] =
        f2bf_bits(pacc[0][ii][c] + pacc[1][ii][c]);
  }
}

// ---------------------------------------------------------------------------
// stage 2: part[sp][b][m] = sum_{n in split sp} polar[b][n] * cart[m][n]
// grid (144 m-tiles of 64, 16 K-splits of 576) = 2304 WGs = 9.0/CU exact.
// Per 2-instr pair each of 16 rows consumes 128B = 2 full lines (no overfetch).
// ---------------------------------------------------------------------------
__global__ __launch_bounds__(256) void k_stage2(
    const u16* __restrict__ polar,             // [64][9216] bf16
    const float* __restrict__ cart,            // [9216][9216] f32
    float* __restrict__ part)                  // [16][64][9216] f32
{
  int tid = threadIdx.x;
  int lane = tid & 63;
  int w = tid >> 6;
  int l15 = lane & 15;
  int m = blockIdx.x * 64 + w * 16 + l15;
  int kg = (lane >> 4) * 8;
  int k0 = blockIdx.y * 576;

  floatx4 acc[4] = {};

  const float* crow = cart + (size_t)m * 9216 + k0 + kg;
  const u16* prow = polar + (size_t)l15 * 9216 + k0 + kg;

  for (int ks = 0; ks < 18; ++ks) {
    floatx4 c0 = *reinterpret_cast<const floatx4*>(crow);
    floatx4 c1 = *reinterpret_cast<const floatx4*>(crow + 4);
    bf16x8 bf;
    bf[0] = (__bf16)c0[0]; bf[1] = (__bf16)c0[1]; bf[2] = (__bf16)c0[2]; bf[3] = (__bf16)c0[3];
    bf[4] = (__bf16)c1[0]; bf[5] = (__bf16)c1[1]; bf[6] = (__bf16)c1[2]; bf[7] = (__bf16)c1[3];
#pragma unroll
    for (int bt = 0; bt < 4; ++bt) {
      bf16x8 af = *reinterpret_cast<const bf16x8*>(prow + bt * 147456);
      acc[bt] = __builtin_amdgcn_mfma_f32_16x16x32_bf16(af, bf, acc[bt], 0, 0, 0);
    }
    crow += 32;
    prow += 32;
  }

  int rg = (lane >> 4) * 4;
#pragma unroll
  for (int bt = 0; bt < 4; ++bt) {
    int b0 = bt * 16 + rg;
#pragma unroll
    for (int q = 0; q < 4; ++q) {
      part[((size_t)blockIdx.y * 64 + b0 + q) * 9216 + m] = acc[bt][q];
    }
  }
}

// ---------------------------------------------------------------------------
// reduce the 16 K-split partials into d_out (f32)
// ---------------------------------------------------------------------------
__global__ __launch_bounds__(256) void k_reduce(
    const float* __restrict__ part, float* __restrict__ out)
{
  int idx = blockIdx.x * 256 + threadIdx.x;    // exactly 589824 threads
  float s = 0.f;
#pragma unroll
  for (int sp = 0; sp < 16; ++sp) s += part[(size_t)sp * 589824 + idx];
  out[idx] = s;
}

// ---------------------------------------------------------------------------
extern "C" void kernel_launch(void* const* d_in, const int* in_sizes, int n_in,
                              void* d_out, int out_size, void* d_ws, size_t ws_size,
                              hipStream_t stream) {
  const float* inputs = (const float*)d_in[0];
  const float* cart   = (const float*)d_in[1];

  char* ws = (char*)d_ws;
  float* Pf   = (float*)(ws + 0);              //   147,456 B
  u16*   Qbf  = (u16*)(ws + 147456);           //    73,728 B
  u16*   polar= (u16*)(ws + 221184);           // 1,179,648 B
  float* part = (float*)(ws + 1400832);        // 37,748,736 B (total ~39.1 MB)

  k_prep<<<144, 256, 0, stream>>>(
      (const float*)d_in[2],  (const float*)d_in[3],  (const float*)d_in[4],  (const float*)d_in[5],
      (const float*)d_in[6],  (const float*)d_in[7],  (const float*)d_in[8],  (const float*)d_in[9],
      (const float*)d_in[10], (const float*)d_in[11], (const float*)d_in[12], (const float*)d_in[13],
      (const float*)d_in[14], (const float*)d_in[15], (const float*)d_in[16], (const float*)d_in[17],
      Pf, Qbf);

  k_stage1<<<1024, 256, 0, stream>>>(inputs, Qbf, Pf, polar);

  k_stage2<<<dim3(144, 16), 256, 0, stream>>>(polar, cart, part);

  k_reduce<<<2304, 256, 0, stream>>>(part, (float*)d_out);
}